// Round 1
// baseline (1032.043 us; speedup 1.0000x reference)
//
#include <hip/hip_runtime.h>
#include <hip/hip_bf16.h>

#define BB 2
#define SS 4096
#define DD 1024
#define HH 16
#define HD 64
#define FF 4096
#define MM (BB*SS)

typedef __hip_bfloat16 bf16;
typedef __attribute__((ext_vector_type(8))) __bf16 v8bf;
typedef __attribute__((ext_vector_type(4))) float f32x4;
typedef __attribute__((ext_vector_type(8))) unsigned short u16v8;

__device__ __forceinline__ f32x4 mfma16(v8bf a, v8bf b, f32x4 c) {
  return __builtin_amdgcn_mfma_f32_16x16x32_bf16(a, b, c, 0, 0, 0);
}

__device__ __forceinline__ void gload16(const void* g, void* l) {
  __builtin_amdgcn_global_load_lds((const __attribute__((address_space(1))) void*)g,
                                   (__attribute__((address_space(3))) void*)l, 16, 0, 0);
}

// ---------------- weight transpose + fp32->bf16 ----------------
// W[K][N] -> Wt[N][K]
__global__ void k_tcvt(const float* __restrict__ W, bf16* __restrict__ Wt, int K, int N)
{
  __shared__ float tile[32][33];
  const int n0 = blockIdx.x * 32, k0 = blockIdx.y * 32;
  const int tx = threadIdx.x, ty = threadIdx.y;
#pragma unroll
  for (int i = 0; i < 32; i += 8)
    tile[ty + i][tx] = W[(long)(k0 + ty + i) * N + n0 + tx];
  __syncthreads();
#pragma unroll
  for (int i = 0; i < 32; i += 8)
    Wt[(long)(n0 + ty + i) * K + k0 + tx] = __float2bfloat16(tile[tx][ty + i]);
}

// ---------------- layernorm: fp32 in -> bf16 out ----------------
__global__ __launch_bounds__(256)
void k_layernorm(const float* __restrict__ x, const float* __restrict__ g,
                 const float* __restrict__ b, bf16* __restrict__ out)
{
  const int row = blockIdx.x;
  const float4 v = ((const float4*)(x + (long)row * DD))[threadIdx.x];
  float s  = v.x + v.y + v.z + v.w;
  float s2 = v.x*v.x + v.y*v.y + v.z*v.z + v.w*v.w;
#pragma unroll
  for (int off = 1; off < 64; off <<= 1) {
    s  += __shfl_xor(s,  off);
    s2 += __shfl_xor(s2, off);
  }
  __shared__ float red[8];
  if ((threadIdx.x & 63) == 0) {
    red[threadIdx.x >> 6]       = s;
    red[(threadIdx.x >> 6) + 4] = s2;
  }
  __syncthreads();
  s  = red[0] + red[1] + red[2] + red[3];
  s2 = red[4] + red[5] + red[6] + red[7];
  const float mu = s * (1.f / DD);
  const float rs = rsqrtf(s2 * (1.f / DD) - mu * mu + 1e-5f);
  const float4 gv = ((const float4*)g)[threadIdx.x];
  const float4 bv = ((const float4*)b)[threadIdx.x];
  bf16* op = out + (long)row * DD + threadIdx.x * 4;
  op[0] = __float2bfloat16((v.x - mu) * rs * gv.x + bv.x);
  op[1] = __float2bfloat16((v.y - mu) * rs * gv.y + bv.y);
  op[2] = __float2bfloat16((v.z - mu) * rs * gv.z + bv.z);
  op[3] = __float2bfloat16((v.w - mu) * rs * gv.w + bv.w);
}

// ---------------- generic bf16 GEMM: C = A[M,K] * Bt[N,K]^T + bias (+res) ----------------
// EPI 0: bf16 out, +bias.  EPI 1: fp32 out, +bias +res (fp32).
template<int EPI>
__global__ __launch_bounds__(256, 2)
void k_gemm(const bf16* __restrict__ A, const bf16* __restrict__ Bt,
            const float* __restrict__ bias, const float* __restrict__ res,
            void* __restrict__ Cout, int M, int N, int K)
{
  __shared__ __align__(16) bf16 As[128 * 32];
  __shared__ __align__(16) bf16 Bs[128 * 32];
  const int t = threadIdx.x;
  const int lane = t & 63, w = t >> 6;
  const int wr = w >> 1, wc = w & 1;
  const int fr = lane & 15, fq = lane >> 4;
  const long m0 = (long)blockIdx.y * 128, n0 = (long)blockIdx.x * 128;

  f32x4 acc[4][4] = {};

  const bf16* Ag0 = A  + (m0 + (t >> 2)) * K + (t & 3) * 8;
  const bf16* Ag1 = Ag0 + 64L * K;
  const bf16* Bg0 = Bt + (n0 + (t >> 2)) * K + (t & 3) * 8;
  const bf16* Bg1 = Bg0 + 64L * K;
  bf16* Al0 = As + t * 8;
  bf16* Al1 = As + 2048 + t * 8;
  bf16* Bl0 = Bs + t * 8;
  bf16* Bl1 = Bs + 2048 + t * 8;

  for (int kk = 0; kk < K; kk += 32) {
    gload16(Ag0 + kk, Al0);
    gload16(Ag1 + kk, Al1);
    gload16(Bg0 + kk, Bl0);
    gload16(Bg1 + kk, Bl1);
    __syncthreads();
    v8bf af[4], bfr[4];
#pragma unroll
    for (int mt = 0; mt < 4; ++mt)
      af[mt] = *(const v8bf*)&As[(wr*64 + mt*16 + fr) * 32 + fq*8];
#pragma unroll
    for (int nt = 0; nt < 4; ++nt)
      bfr[nt] = *(const v8bf*)&Bs[(wc*64 + nt*16 + fr) * 32 + fq*8];
#pragma unroll
    for (int mt = 0; mt < 4; ++mt)
#pragma unroll
      for (int nt = 0; nt < 4; ++nt)
        acc[mt][nt] = mfma16(af[mt], bfr[nt], acc[mt][nt]);
    __syncthreads();
  }

#pragma unroll
  for (int nt = 0; nt < 4; ++nt) {
    const long col = n0 + wc*64 + nt*16 + fr;
    const float bv = bias[col];
#pragma unroll
    for (int mt = 0; mt < 4; ++mt) {
#pragma unroll
      for (int j = 0; j < 4; ++j) {
        const long row = m0 + wr*64 + mt*16 + fq*4 + j;
        float v = acc[mt][nt][j] + bv;
        if (EPI == 0) {
          ((bf16*)Cout)[row * N + col] = __float2bfloat16(v);
        } else {
          v += res[row * N + col];
          ((float*)Cout)[row * N + col] = v;
        }
      }
    }
  }
}

// ---------------- dual FFN GEMM: prod = sigmoid(A*Wg+bg) * gelu(A*W1+b1) ----------------
// 128x64 tile. BgT/BuT are [FF, D] bf16.
__global__ __launch_bounds__(256, 2)
void k_ffn_dual(const bf16* __restrict__ A, const bf16* __restrict__ BgT,
                const bf16* __restrict__ BuT, const float* __restrict__ bgb,
                const float* __restrict__ bub, bf16* __restrict__ Out)
{
  __shared__ __align__(16) bf16 As[128 * 32];
  __shared__ __align__(16) bf16 Gs[64 * 32];
  __shared__ __align__(16) bf16 Us[64 * 32];
  const int t = threadIdx.x;
  const int lane = t & 63, w = t >> 6;
  const int wr = w >> 1, wc = w & 1;
  const int fr = lane & 15, fq = lane >> 4;
  const long m0 = (long)blockIdx.y * 128, n0 = (long)blockIdx.x * 64;
  const int K = DD;

  f32x4 ag[4][2] = {}, au[4][2] = {};

  const bf16* Ag0 = A   + (m0 + (t >> 2)) * K + (t & 3) * 8;
  const bf16* Ag1 = Ag0 + 64L * K;
  const bf16* Gg  = BgT + (n0 + (t >> 2)) * K + (t & 3) * 8;
  const bf16* Ug  = BuT + (n0 + (t >> 2)) * K + (t & 3) * 8;

  for (int kk = 0; kk < K; kk += 32) {
    gload16(Ag0 + kk, As + t * 8);
    gload16(Ag1 + kk, As + 2048 + t * 8);
    gload16(Gg + kk, Gs + t * 8);
    gload16(Ug + kk, Us + t * 8);
    __syncthreads();
    v8bf af[4], gf[2], uf[2];
#pragma unroll
    for (int mt = 0; mt < 4; ++mt)
      af[mt] = *(const v8bf*)&As[(wr*64 + mt*16 + fr) * 32 + fq*8];
#pragma unroll
    for (int nt = 0; nt < 2; ++nt) {
      gf[nt] = *(const v8bf*)&Gs[(wc*32 + nt*16 + fr) * 32 + fq*8];
      uf[nt] = *(const v8bf*)&Us[(wc*32 + nt*16 + fr) * 32 + fq*8];
    }
#pragma unroll
    for (int mt = 0; mt < 4; ++mt)
#pragma unroll
      for (int nt = 0; nt < 2; ++nt) {
        ag[mt][nt] = mfma16(af[mt], gf[nt], ag[mt][nt]);
        au[mt][nt] = mfma16(af[mt], uf[nt], au[mt][nt]);
      }
    __syncthreads();
  }

#pragma unroll
  for (int nt = 0; nt < 2; ++nt) {
    const long col = n0 + wc*32 + nt*16 + fr;
    const float gb = bgb[col], ub = bub[col];
#pragma unroll
    for (int mt = 0; mt < 4; ++mt) {
#pragma unroll
      for (int j = 0; j < 4; ++j) {
        const long row = m0 + wr*64 + mt*16 + fq*4 + j;
        const float g = ag[mt][nt][j] + gb;
        const float u = au[mt][nt][j] + ub;
        const float sg = 1.f / (1.f + __expf(-g));
        const float gl = 0.5f * u * (1.f + erff(u * 0.70710678118f));
        Out[row * FF + col] = __float2bfloat16(sg * gl);
      }
    }
  }
}

// ---------------- flash attention ----------------
// Q/K/V/ctx stored [B*S, D] bf16 with col = h*64+hd. grid (S/64, H, B), 256 thr.
__global__ __launch_bounds__(256, 2)
void k_attn(const bf16* __restrict__ Qb, const bf16* __restrict__ Kb,
            const bf16* __restrict__ Vb, bf16* __restrict__ ctx)
{
  __shared__ __align__(16) bf16 P[64][72];
  __shared__ __align__(16) bf16 Vt[64][72];
  const int t = threadIdx.x, lane = t & 63, w = t >> 6;
  const int fr = lane & 15, fq = lane >> 4;
  const int q0 = blockIdx.x * 64;
  const long base = ((long)blockIdx.z * SS) * DD + blockIdx.y * HD;

  v8bf qf[2];
  {
    const bf16* qp = Qb + base + (long)(q0 + w*16 + fr) * DD + fq*8;
    qf[0] = *(const v8bf*)qp;
    qf[1] = *(const v8bf*)(qp + 32);
  }

  float m_[4] = {-1e30f, -1e30f, -1e30f, -1e30f};
  float l_[4] = {0.f, 0.f, 0.f, 0.f};
  f32x4 o_[4] = {};

  for (int kv0 = 0; kv0 < SS; kv0 += 64) {
    // scores: S = Q K^T  (per wave: 16 q-rows x 64 kv)
    f32x4 sa[4] = {};
#pragma unroll
    for (int nt = 0; nt < 4; ++nt) {
      const bf16* kp = Kb + base + (long)(kv0 + nt*16 + fr) * DD + fq*8;
      sa[nt] = mfma16(qf[0], *(const v8bf*)kp, sa[nt]);
      sa[nt] = mfma16(qf[1], *(const v8bf*)(kp + 32), sa[nt]);
    }
    // online softmax (row r = fq*4+j lives in 16-lane group; cols = nt*16+fr)
    float alpha[4];
#pragma unroll
    for (int j = 0; j < 4; ++j) {
#pragma unroll
      for (int nt = 0; nt < 4; ++nt) sa[nt][j] *= 0.125f;
      float rm = fmaxf(fmaxf(sa[0][j], sa[1][j]), fmaxf(sa[2][j], sa[3][j]));
      rm = fmaxf(rm, __shfl_xor(rm, 1));
      rm = fmaxf(rm, __shfl_xor(rm, 2));
      rm = fmaxf(rm, __shfl_xor(rm, 4));
      rm = fmaxf(rm, __shfl_xor(rm, 8));
      const float mn = fmaxf(m_[j], rm);
      alpha[j] = __expf(m_[j] - mn);
      m_[j] = mn;
      float rs = 0.f;
#pragma unroll
      for (int nt = 0; nt < 4; ++nt) {
        const float p = __expf(sa[nt][j] - mn);
        sa[nt][j] = p;
        rs += p;
      }
      rs += __shfl_xor(rs, 1);
      rs += __shfl_xor(rs, 2);
      rs += __shfl_xor(rs, 4);
      rs += __shfl_xor(rs, 8);
      l_[j] = l_[j] * alpha[j] + rs;
    }
#pragma unroll
    for (int ht = 0; ht < 4; ++ht)
#pragma unroll
      for (int j = 0; j < 4; ++j) o_[ht][j] *= alpha[j];

    __syncthreads();  // all waves done reading Vt from previous tile
    // write P (own 16 rows), stage V^T cooperatively
#pragma unroll
    for (int nt = 0; nt < 4; ++nt)
#pragma unroll
      for (int j = 0; j < 4; ++j)
        P[w*16 + fq*4 + j][nt*16 + fr] = __float2bfloat16(sa[nt][j]);
#pragma unroll
    for (int it = 0; it < 2; ++it) {
      const int kvr = it * 32 + (t >> 3);
      const u16v8 vv = *(const u16v8*)(Vb + base + (long)(kv0 + kvr) * DD + (t & 7) * 8);
#pragma unroll
      for (int e = 0; e < 8; ++e)
        ((unsigned short*)Vt)[((t & 7) * 8 + e) * 72 + kvr] = vv[e];
    }
    __syncthreads();  // Vt ready
    // O += P * V
#pragma unroll
    for (int ht = 0; ht < 4; ++ht) {
#pragma unroll
      for (int ks = 0; ks < 2; ++ks) {
        const v8bf pf = *(const v8bf*)&P[w*16 + fr][ks*32 + fq*8];
        const v8bf vf = *(const v8bf*)&Vt[ht*16 + fr][ks*32 + fq*8];
        o_[ht] = mfma16(pf, vf, o_[ht]);
      }
    }
  }

#pragma unroll
  for (int ht = 0; ht < 4; ++ht)
#pragma unroll
    for (int j = 0; j < 4; ++j) {
      const long row = q0 + w*16 + fq*4 + j;
      ctx[base + row * DD + ht*16 + fr] = __float2bfloat16(o_[ht][j] / l_[j]);
    }
}

// ---------------- host ----------------
extern "C" void kernel_launch(void* const* d_in, const int* in_sizes, int n_in,
                              void* d_out, int out_size, void* d_ws, size_t ws_size,
                              hipStream_t stream)
{
  const float* x    = (const float*)d_in[0];
  const float* wq   = (const float*)d_in[1];
  const float* bq   = (const float*)d_in[2];
  const float* wk   = (const float*)d_in[3];
  const float* bk   = (const float*)d_in[4];
  const float* wv   = (const float*)d_in[5];
  const float* bv   = (const float*)d_in[6];
  const float* wo   = (const float*)d_in[7];
  const float* bo   = (const float*)d_in[8];
  const float* ln1g = (const float*)d_in[9];
  const float* ln1b = (const float*)d_in[10];
  const float* lnfg = (const float*)d_in[11];
  const float* lnfb = (const float*)d_in[12];
  const float* w1   = (const float*)d_in[13];
  const float* b1   = (const float*)d_in[14];
  const float* wg   = (const float*)d_in[15];
  const float* bg   = (const float*)d_in[16];
  const float* w2   = (const float*)d_in[17];
  const float* b2   = (const float*)d_in[18];

  char* ws = (char*)d_ws;
  const size_t MB = 1u << 20;
  bf16*  WqT  = (bf16*)(ws + 0 * MB);     // [1024,1024]  2MB
  bf16*  WkT  = (bf16*)(ws + 2 * MB);
  bf16*  WvT  = (bf16*)(ws + 4 * MB);
  bf16*  WoT  = (bf16*)(ws + 6 * MB);
  bf16*  W1T  = (bf16*)(ws + 8 * MB);     // [4096,1024]  8MB
  bf16*  WgT  = (bf16*)(ws + 16 * MB);
  bf16*  W2T  = (bf16*)(ws + 24 * MB);    // [1024,4096]  8MB
  float* x1   = (float*)(ws + 32 * MB);   // [8192,1024] f32 32MB
  bf16*  hbuf = (bf16*)(ws + 64 * MB);    // [8192,1024] 16MB (h then h2)
  bf16*  Qb   = (bf16*)(ws + 80 * MB);
  bf16*  Kb   = (bf16*)(ws + 96 * MB);
  bf16*  Vb   = (bf16*)(ws + 112 * MB);
  bf16*  ctx  = (bf16*)(ws + 128 * MB);
  bf16*  prod = (bf16*)(ws + 80 * MB);    // [8192,4096] 64MB, overlaps Q/K/V/ctx (dead)

  dim3 tb(32, 8);
  k_tcvt<<<dim3(32, 32), tb, 0, stream>>>(wq, WqT, 1024, 1024);
  k_tcvt<<<dim3(32, 32), tb, 0, stream>>>(wk, WkT, 1024, 1024);
  k_tcvt<<<dim3(32, 32), tb, 0, stream>>>(wv, WvT, 1024, 1024);
  k_tcvt<<<dim3(32, 32), tb, 0, stream>>>(wo, WoT, 1024, 1024);
  k_tcvt<<<dim3(128, 32), tb, 0, stream>>>(w1, W1T, 1024, 4096);
  k_tcvt<<<dim3(128, 32), tb, 0, stream>>>(wg, WgT, 1024, 4096);
  k_tcvt<<<dim3(32, 128), tb, 0, stream>>>(w2, W2T, 4096, 1024);

  k_layernorm<<<MM, 256, 0, stream>>>(x, ln1g, ln1b, hbuf);

  dim3 g1(1024 / 128, MM / 128);
  k_gemm<0><<<g1, 256, 0, stream>>>(hbuf, WqT, bq, nullptr, Qb, MM, 1024, 1024);
  k_gemm<0><<<g1, 256, 0, stream>>>(hbuf, WkT, bk, nullptr, Kb, MM, 1024, 1024);
  k_gemm<0><<<g1, 256, 0, stream>>>(hbuf, WvT, bv, nullptr, Vb, MM, 1024, 1024);

  k_attn<<<dim3(SS / 64, HH, BB), 256, 0, stream>>>(Qb, Kb, Vb, ctx);

  k_gemm<1><<<g1, 256, 0, stream>>>(ctx, WoT, bo, x, x1, MM, 1024, 1024);

  k_layernorm<<<MM, 256, 0, stream>>>(x1, lnfg, lnfb, hbuf);

  k_ffn_dual<<<dim3(FF / 64, MM / 128), 256, 0, stream>>>(hbuf, WgT, W1T, bg, b1, prod);

  k_gemm<1><<<g1, 256, 0, stream>>>(prod, W2T, b2, x1, (float*)d_out, MM, 1024, 4096);
}

// Round 4
// 637.572 us; speedup vs baseline: 1.6187x; 1.6187x over previous
//
#include <hip/hip_runtime.h>
#include <hip/hip_bf16.h>

#define BB 2
#define SS 4096
#define DD 1024
#define HH 16
#define HD 64
#define FF 4096
#define MM (BB*SS)

typedef __hip_bfloat16 bf16;
typedef __attribute__((ext_vector_type(8))) __bf16 v8bf;
typedef __attribute__((ext_vector_type(4))) float f32x4;
typedef __attribute__((ext_vector_type(16))) float f32x16;
typedef __attribute__((ext_vector_type(8))) unsigned short u16v8;

__device__ __forceinline__ f32x4 mfma16(v8bf a, v8bf b, f32x4 c) {
  return __builtin_amdgcn_mfma_f32_16x16x32_bf16(a, b, c, 0, 0, 0);
}
__device__ __forceinline__ f32x16 mfma32(v8bf a, v8bf b, f32x16 c) {
  return __builtin_amdgcn_mfma_f32_32x32x16_bf16(a, b, c, 0, 0, 0);
}
__device__ __forceinline__ void gload16(const void* g, void* l) {
  __builtin_amdgcn_global_load_lds((const __attribute__((address_space(1))) void*)g,
                                   (__attribute__((address_space(3))) void*)l, 16, 0, 0);
}
__device__ __forceinline__ unsigned cvtpk_bf16(float lo, float hi) {
  unsigned r;
  asm("v_cvt_pk_bf16_f32 %0, %1, %2" : "=v"(r) : "v"(lo), "v"(hi));
  return r;
}

// ---------------- weight transpose + fp32->bf16 ----------------
__global__ void k_tcvt(const float* __restrict__ W, bf16* __restrict__ Wt, int K, int N)
{
  __shared__ float tile[32][33];
  const int n0 = blockIdx.x * 32, k0 = blockIdx.y * 32;
  const int tx = threadIdx.x, ty = threadIdx.y;
#pragma unroll
  for (int i = 0; i < 32; i += 8)
    tile[ty + i][tx] = W[(long)(k0 + ty + i) * N + n0 + tx];
  __syncthreads();
#pragma unroll
  for (int i = 0; i < 32; i += 8)
    Wt[(long)(n0 + ty + i) * K + k0 + tx] = __float2bfloat16(tile[tx][ty + i]);
}

// ---------------- layernorm: fp32 in -> bf16 out ----------------
__global__ __launch_bounds__(256)
void k_layernorm(const float* __restrict__ x, const float* __restrict__ g,
                 const float* __restrict__ b, bf16* __restrict__ out)
{
  const int row = blockIdx.x;
  const float4 v = ((const float4*)(x + (long)row * DD))[threadIdx.x];
  float s  = v.x + v.y + v.z + v.w;
  float s2 = v.x*v.x + v.y*v.y + v.z*v.z + v.w*v.w;
#pragma unroll
  for (int off = 1; off < 64; off <<= 1) {
    s  += __shfl_xor(s,  off);
    s2 += __shfl_xor(s2, off);
  }
  __shared__ float red[8];
  if ((threadIdx.x & 63) == 0) {
    red[threadIdx.x >> 6]       = s;
    red[(threadIdx.x >> 6) + 4] = s2;
  }
  __syncthreads();
  s  = red[0] + red[1] + red[2] + red[3];
  s2 = red[4] + red[5] + red[6] + red[7];
  const float mu = s * (1.f / DD);
  const float rs = rsqrtf(s2 * (1.f / DD) - mu * mu + 1e-5f);
  const float4 gv = ((const float4*)g)[threadIdx.x];
  const float4 bv = ((const float4*)b)[threadIdx.x];
  bf16* op = out + (long)row * DD + threadIdx.x * 4;
  op[0] = __float2bfloat16((v.x - mu) * rs * gv.x + bv.x);
  op[1] = __float2bfloat16((v.y - mu) * rs * gv.y + bv.y);
  op[2] = __float2bfloat16((v.z - mu) * rs * gv.z + bv.z);
  op[3] = __float2bfloat16((v.w - mu) * rs * gv.w + bv.w);
}

// ---------------- generic bf16 GEMM: C = (A[M,K] * Bt[N,K]^T + bias)*scale ----------------
// EPI 0: bf16 out.  EPI 1: fp32 out +res.  EPI 2: bf16 out, V-transposed scatter.
template<int EPI>
__global__ __launch_bounds__(256, 2)
void k_gemm(const bf16* __restrict__ A, const bf16* __restrict__ Bt,
            const float* __restrict__ bias, const float* __restrict__ res,
            void* __restrict__ Cout, int M, int N, int K, float scale)
{
  __shared__ __align__(16) bf16 As[128 * 32];
  __shared__ __align__(16) bf16 Bs[128 * 32];
  const int t = threadIdx.x;
  const int lane = t & 63, w = t >> 6;
  const int wr = w >> 1, wc = w & 1;
  const int fr = lane & 15, fq = lane >> 4;
  const long m0 = (long)blockIdx.y * 128, n0 = (long)blockIdx.x * 128;

  f32x4 acc[4][4] = {};

  const bf16* Ag0 = A  + (m0 + (t >> 2)) * K + (t & 3) * 8;
  const bf16* Ag1 = Ag0 + 64L * K;
  const bf16* Bg0 = Bt + (n0 + (t >> 2)) * K + (t & 3) * 8;
  const bf16* Bg1 = Bg0 + 64L * K;
  bf16* Al0 = As + t * 8;
  bf16* Al1 = As + 2048 + t * 8;
  bf16* Bl0 = Bs + t * 8;
  bf16* Bl1 = Bs + 2048 + t * 8;

  for (int kk = 0; kk < K; kk += 32) {
    gload16(Ag0 + kk, Al0);
    gload16(Ag1 + kk, Al1);
    gload16(Bg0 + kk, Bl0);
    gload16(Bg1 + kk, Bl1);
    __syncthreads();
    v8bf af[4], bfr[4];
#pragma unroll
    for (int mt = 0; mt < 4; ++mt)
      af[mt] = *(const v8bf*)&As[(wr*64 + mt*16 + fr) * 32 + fq*8];
#pragma unroll
    for (int nt = 0; nt < 4; ++nt)
      bfr[nt] = *(const v8bf*)&Bs[(wc*64 + nt*16 + fr) * 32 + fq*8];
#pragma unroll
    for (int mt = 0; mt < 4; ++mt)
#pragma unroll
      for (int nt = 0; nt < 4; ++nt)
        acc[mt][nt] = mfma16(af[mt], bfr[nt], acc[mt][nt]);
    __syncthreads();
  }

#pragma unroll
  for (int nt = 0; nt < 4; ++nt) {
    const long col = n0 + wc*64 + nt*16 + fr;
    const float bv = bias[col];
#pragma unroll
    for (int mt = 0; mt < 4; ++mt) {
#pragma unroll
      for (int j = 0; j < 4; ++j) {
        const long row = m0 + wr*64 + mt*16 + fq*4 + j;
        float v = (acc[mt][nt][j] + bv) * scale;
        if (EPI == 0) {
          ((bf16*)Cout)[row * N + col] = __float2bfloat16(v);
        } else if (EPI == 1) {
          ((float*)Cout)[row * N + col] = v + res[row * N + col];
        } else {
          // V transposed per head: Vt[(b*HH+h)*HD + d][s]
          const long s = row & (SS - 1), bb = row >> 12;
          ((bf16*)Cout)[((bb * HH + (col >> 6)) * HD + (col & 63)) * (long)SS + s] =
              __float2bfloat16(v);
        }
      }
    }
  }
}

// ---------------- dual FFN GEMM: prod = sigmoid(A*Wg+bg) * gelu(A*W1+b1) ----------------
__global__ __launch_bounds__(256, 2)
void k_ffn_dual(const bf16* __restrict__ A, const bf16* __restrict__ BgT,
                const bf16* __restrict__ BuT, const float* __restrict__ bgb,
                const float* __restrict__ bub, bf16* __restrict__ Out)
{
  __shared__ __align__(16) bf16 As[128 * 32];
  __shared__ __align__(16) bf16 Gs[64 * 32];
  __shared__ __align__(16) bf16 Us[64 * 32];
  const int t = threadIdx.x;
  const int lane = t & 63, w = t >> 6;
  const int wr = w >> 1, wc = w & 1;
  const int fr = lane & 15, fq = lane >> 4;
  const long m0 = (long)blockIdx.y * 128, n0 = (long)blockIdx.x * 64;
  const int K = DD;

  f32x4 ag[4][2] = {}, au[4][2] = {};

  const bf16* Ag0 = A   + (m0 + (t >> 2)) * K + (t & 3) * 8;
  const bf16* Ag1 = Ag0 + 64L * K;
  const bf16* Gg  = BgT + (n0 + (t >> 2)) * K + (t & 3) * 8;
  const bf16* Ug  = BuT + (n0 + (t >> 2)) * K + (t & 3) * 8;

  for (int kk = 0; kk < K; kk += 32) {
    gload16(Ag0 + kk, As + t * 8);
    gload16(Ag1 + kk, As + 2048 + t * 8);
    gload16(Gg + kk, Gs + t * 8);
    gload16(Ug + kk, Us + t * 8);
    __syncthreads();
    v8bf af[4], gf[2], uf[2];
#pragma unroll
    for (int mt = 0; mt < 4; ++mt)
      af[mt] = *(const v8bf*)&As[(wr*64 + mt*16 + fr) * 32 + fq*8];
#pragma unroll
    for (int nt = 0; nt < 2; ++nt) {
      gf[nt] = *(const v8bf*)&Gs[(wc*32 + nt*16 + fr) * 32 + fq*8];
      uf[nt] = *(const v8bf*)&Us[(wc*32 + nt*16 + fr) * 32 + fq*8];
    }
#pragma unroll
    for (int mt = 0; mt < 4; ++mt)
#pragma unroll
      for (int nt = 0; nt < 2; ++nt) {
        ag[mt][nt] = mfma16(af[mt], gf[nt], ag[mt][nt]);
        au[mt][nt] = mfma16(af[mt], uf[nt], au[mt][nt]);
      }
    __syncthreads();
  }

#pragma unroll
  for (int nt = 0; nt < 2; ++nt) {
    const long col = n0 + wc*32 + nt*16 + fr;
    const float gb = bgb[col], ub = bub[col];
#pragma unroll
    for (int mt = 0; mt < 4; ++mt) {
#pragma unroll
      for (int j = 0; j < 4; ++j) {
        const long row = m0 + wr*64 + mt*16 + fq*4 + j;
        const float g = ag[mt][nt][j] + gb;
        const float u = au[mt][nt][j] + ub;
        const float sg = 1.f / (1.f + __expf(-g));
        const float gl = 0.5f * u * (1.f + erff(u * 0.70710678118f));
        Out[row * FF + col] = __float2bfloat16(sg * gl);
      }
    }
  }
}

// ---------------- flash attention, 4 waves x 32 q-rows, 32x32x16 MFMA ----------------
// Qb/Kb: [B*S, D] bf16 (Q pre-scaled by 0.125*log2e). Vt: [B*H, 64, S] bf16.
// grid (S/128, H, B), 256 threads.
__global__ __launch_bounds__(256, 2)
void k_attn(const bf16* __restrict__ Qb, const bf16* __restrict__ Kb,
            const bf16* __restrict__ Vt, bf16* __restrict__ ctx)
{
  __shared__ __align__(16) bf16 Ksh[2][4096];
  __shared__ __align__(16) bf16 Vsh[2][4096];
  const int t = threadIdx.x;
  const int lane = t & 63, w = t >> 6;
  const int q5 = lane & 31, hi = lane >> 5;
  const int q0 = blockIdx.x * 128;
  const int h = blockIdx.y, b = blockIdx.z;
  const long qk_base = ((long)b * SS) * DD + h * HD;
  const long vt_base = ((long)(b * HH + h)) * ((long)HD * SS);

  // staging source addresses (pre-swizzled so LDS stays linear; read applies same XOR)
  const int r0 = t >> 3;                               // row 0..31 within 32-row chunk
  const int cswz = ((t & 7) * 16) ^ ((r0 & 7) << 4);   // byte col, XOR-swizzled
  const bf16* kg = Kb + qk_base + (long)r0 * DD + (cswz >> 1);
  const bf16* vg = Vt + vt_base + (long)r0 * SS + (cswz >> 1);

  // Q fragments (B-operand): lane holds Q[q0+w*32+q5][c*16 + hi*8 + 0..7]
  v8bf qf[4];
  {
    const bf16* qp = Qb + qk_base + (long)(q0 + w * 32 + q5) * DD + hi * 8;
#pragma unroll
    for (int c = 0; c < 4; ++c) qf[c] = *(const v8bf*)(qp + c * 16);
  }

  // swizzled LDS col offsets (elements) for fragment reads
  int kcol[4];
#pragma unroll
  for (int c = 0; c < 4; ++c)
    kcol[c] = ((c * 32 + hi * 16) ^ ((q5 & 7) << 4)) >> 1;

  float m_ = -1e30f, l_ = 0.f;
  f32x16 o0 = {}, o1 = {};

#define STAGE(bufidx, kv0_) do {                                  \
    const bf16* kp_ = kg + (long)(kv0_) * DD;                     \
    gload16(kp_,            &Ksh[bufidx][t * 8]);                 \
    gload16(kp_ + 32L * DD, &Ksh[bufidx][2048 + t * 8]);          \
    const bf16* vp_ = vg + (kv0_);                                \
    gload16(vp_,            &Vsh[bufidx][t * 8]);                 \
    gload16(vp_ + 32L * SS, &Vsh[bufidx][2048 + t * 8]);          \
  } while (0)

  STAGE(0, 0);
  __syncthreads();

  for (int tt = 0; tt < SS / 64; ++tt) {
    const int cur = tt & 1;
    if (tt + 1 < SS / 64) STAGE(cur ^ 1, (tt + 1) * 64);

    // S^T = K * Q^T : lane holds S[q = q0+w*32+q5][32 kv values]
    f32x16 s0 = {}, s1 = {};
#pragma unroll
    for (int c = 0; c < 4; ++c) {
      const v8bf k0 = *(const v8bf*)&Ksh[cur][q5 * 64 + kcol[c]];
      const v8bf k1 = *(const v8bf*)&Ksh[cur][(32 + q5) * 64 + kcol[c]];
      s0 = mfma32(k0, qf[c], s0);
      s1 = mfma32(k1, qf[c], s1);
    }

    // online softmax, log2-domain (scale folded into Q)
    float pm = s0[0];
#pragma unroll
    for (int r = 1; r < 16; ++r) pm = fmaxf(pm, s0[r]);
#pragma unroll
    for (int r = 0; r < 16; ++r) pm = fmaxf(pm, s1[r]);
    pm = fmaxf(pm, __shfl_xor(pm, 32));
    const float mn = fmaxf(m_, pm);
    const float al = __builtin_amdgcn_exp2f(m_ - mn);
    m_ = mn;
    float rs = 0.f;
#pragma unroll
    for (int r = 0; r < 16; ++r) { s0[r] = __builtin_amdgcn_exp2f(s0[r] - mn); rs += s0[r]; }
#pragma unroll
    for (int r = 0; r < 16; ++r) { s1[r] = __builtin_amdgcn_exp2f(s1[r] - mn); rs += s1[r]; }
    rs += __shfl_xor(rs, 32);
    l_ = l_ * al + rs;
#pragma unroll
    for (int r = 0; r < 16; ++r) { o0[r] *= al; o1[r] *= al; }

    // pack P into PV B-fragments: pb[c][e] = P[q][c*16 + hi*8 + e]
    v8bf pb[4];
#pragma unroll
    for (int c = 0; c < 4; ++c) {
      const int base = (c & 1) * 8;
      unsigned wa0, wa1, wb0, wb1;
      if (c < 2) {
        wa0 = cvtpk_bf16(s0[base + 0], s0[base + 1]);
        wa1 = cvtpk_bf16(s0[base + 2], s0[base + 3]);
        wb0 = cvtpk_bf16(s0[base + 4], s0[base + 5]);
        wb1 = cvtpk_bf16(s0[base + 6], s0[base + 7]);
      } else {
        wa0 = cvtpk_bf16(s1[base + 0], s1[base + 1]);
        wa1 = cvtpk_bf16(s1[base + 2], s1[base + 3]);
        wb0 = cvtpk_bf16(s1[base + 4], s1[base + 5]);
        wb1 = cvtpk_bf16(s1[base + 6], s1[base + 7]);
      }
      // swap vdst.high <-> vsrc.low: vdst = low-element word (wa), vsrc = high (wb)
      asm("v_permlane32_swap_b32 %0, %1" : "+v"(wa0), "+v"(wb0));
      asm("v_permlane32_swap_b32 %0, %1" : "+v"(wa1), "+v"(wb1));
      union { unsigned u[4]; v8bf v; } cvt;
      cvt.u[0] = wa0; cvt.u[1] = wa1; cvt.u[2] = wb0; cvt.u[3] = wb1;
      pb[c] = cvt.v;
    }

    // O^T += V^T * P : lane holds O[d rows][q = lane&31 (+w*32)]
#pragma unroll
    for (int c = 0; c < 4; ++c) {
      const v8bf v0f = *(const v8bf*)&Vsh[cur][q5 * 64 + kcol[c]];
      const v8bf v1f = *(const v8bf*)&Vsh[cur][(32 + q5) * 64 + kcol[c]];
      o0 = mfma32(v0f, pb[c], o0);
      o1 = mfma32(v1f, pb[c], o1);
    }
    __syncthreads();
  }
#undef STAGE

  // transpose O through LDS for coalesced stores
  const float inv = 1.f / l_;
  bf16* Osh = &Ksh[0][0];  // 16 KB, safe after final barrier
  const int qrow = w * 32 + q5;
  const int oswz = (qrow & 7) << 4;
#pragma unroll
  for (int r = 0; r < 16; ++r) {
    const int d0 = (r & 3) + 8 * (r >> 2) + 4 * hi;
    Osh[((qrow * 128 + d0 * 2) ^ oswz) >> 1]        = __float2bfloat16(o0[r] * inv);
    Osh[((qrow * 128 + (32 + d0) * 2) ^ oswz) >> 1] = __float2bfloat16(o1[r] * inv);
  }
  __syncthreads();
  {
    const int q = t >> 1, half = t & 1;
    const int qs = (q & 7) << 4;
    bf16* cp = ctx + qk_base + (long)(q0 + q) * DD + half * 32;
#pragma unroll
    for (int s = 0; s < 4; ++s) {
      const int byte = (q * 128 + half * 64 + s * 16) ^ qs;
      *(u16v8*)(cp + s * 8) = *(const u16v8*)&Osh[byte >> 1];
    }
  }
}

// ---------------- host ----------------
extern "C" void kernel_launch(void* const* d_in, const int* in_sizes, int n_in,
                              void* d_out, int out_size, void* d_ws, size_t ws_size,
                              hipStream_t stream)
{
  const float* x    = (const float*)d_in[0];
  const float* wq   = (const float*)d_in[1];
  const float* bq   = (const float*)d_in[2];
  const float* wk   = (const float*)d_in[3];
  const float* bk   = (const float*)d_in[4];
  const float* wv   = (const float*)d_in[5];
  const float* bv   = (const float*)d_in[6];
  const float* wo   = (const float*)d_in[7];
  const float* bo   = (const float*)d_in[8];
  const float* ln1g = (const float*)d_in[9];
  const float* ln1b = (const float*)d_in[10];
  const float* lnfg = (const float*)d_in[11];
  const float* lnfb = (const float*)d_in[12];
  const float* w1   = (const float*)d_in[13];
  const float* b1   = (const float*)d_in[14];
  const float* wg   = (const float*)d_in[15];
  const float* bg   = (const float*)d_in[16];
  const float* w2   = (const float*)d_in[17];
  const float* b2   = (const float*)d_in[18];

  char* ws = (char*)d_ws;
  const size_t MB = 1u << 20;
  bf16*  WqT  = (bf16*)(ws + 0 * MB);
  bf16*  WkT  = (bf16*)(ws + 2 * MB);
  bf16*  WvT  = (bf16*)(ws + 4 * MB);
  bf16*  WoT  = (bf16*)(ws + 6 * MB);
  bf16*  W1T  = (bf16*)(ws + 8 * MB);
  bf16*  WgT  = (bf16*)(ws + 16 * MB);
  bf16*  W2T  = (bf16*)(ws + 24 * MB);
  float* x1   = (float*)(ws + 32 * MB);
  bf16*  hbuf = (bf16*)(ws + 64 * MB);
  bf16*  Qb   = (bf16*)(ws + 80 * MB);
  bf16*  Kb   = (bf16*)(ws + 96 * MB);
  bf16*  Vtb  = (bf16*)(ws + 112 * MB);   // [B*H][64][S] transposed V
  bf16*  ctxb = (bf16*)(ws + 128 * MB);
  bf16*  prod = (bf16*)(ws + 80 * MB);    // overlaps Q/K/Vt/ctx (dead by then)

  dim3 tb(32, 8);
  k_tcvt<<<dim3(32, 32), tb, 0, stream>>>(wq, WqT, 1024, 1024);
  k_tcvt<<<dim3(32, 32), tb, 0, stream>>>(wk, WkT, 1024, 1024);
  k_tcvt<<<dim3(32, 32), tb, 0, stream>>>(wv, WvT, 1024, 1024);
  k_tcvt<<<dim3(32, 32), tb, 0, stream>>>(wo, WoT, 1024, 1024);
  k_tcvt<<<dim3(128, 32), tb, 0, stream>>>(w1, W1T, 1024, 4096);
  k_tcvt<<<dim3(128, 32), tb, 0, stream>>>(wg, WgT, 1024, 4096);
  k_tcvt<<<dim3(32, 128), tb, 0, stream>>>(w2, W2T, 4096, 1024);

  k_layernorm<<<MM, 256, 0, stream>>>(x, ln1g, ln1b, hbuf);

  const float qscale = 0.1803368801111204f;  // log2(e) / sqrt(64)
  dim3 g1(1024 / 128, MM / 128);
  k_gemm<0><<<g1, 256, 0, stream>>>(hbuf, WqT, bq, nullptr, Qb, MM, 1024, 1024, qscale);
  k_gemm<0><<<g1, 256, 0, stream>>>(hbuf, WkT, bk, nullptr, Kb, MM, 1024, 1024, 1.f);
  k_gemm<2><<<g1, 256, 0, stream>>>(hbuf, WvT, bv, nullptr, Vtb, MM, 1024, 1024, 1.f);

  k_attn<<<dim3(SS / 128, HH, BB), 256, 0, stream>>>(Qb, Kb, Vtb, ctxb);

  k_gemm<1><<<g1, 256, 0, stream>>>(ctxb, WoT, bo, x, x1, MM, 1024, 1024, 1.f);

  k_layernorm<<<MM, 256, 0, stream>>>(x1, lnfg, lnfb, hbuf);

  k_ffn_dual<<<dim3(FF / 64, MM / 128), 256, 0, stream>>>(hbuf, WgT, W1T, bg, b1, prod);

  k_gemm<1><<<g1, 256, 0, stream>>>(prod, W2T, b2, x1, (float*)d_out, MM, 1024, 4096, 1.f);
}